// Round 1
// baseline (448.001 us; speedup 1.0000x reference)
//
#include <hip/hip_runtime.h>
#include <hip/hip_bf16.h>
#include <cstdint>
#include <cstddef>

// Problem constants
#define BB   512
#define NN   100
#define HH   768
#define II   1536
#define MM   (BB*NN)          // 51200 rows

typedef __bf16 bf16;
typedef __bf16 bf16x4 __attribute__((ext_vector_type(4)));
typedef __bf16 bf16x8 __attribute__((ext_vector_type(8)));
typedef float  f32x4  __attribute__((ext_vector_type(4)));

// async global -> LDS, 16B per lane (wave-uniform LDS base + lane*16)
__device__ __forceinline__ void gld_lds16(const bf16* g, bf16* l) {
    __builtin_amdgcn_global_load_lds(
        (const __attribute__((address_space(1))) void*)g,
        (__attribute__((address_space(3))) void*)l, 16, 0, 0);
}

// butterfly add over 16-lane groups via ds_swizzle (BitMode, single DS inst)
template <int PAT>
__device__ __forceinline__ float swz_add(float x) {
    return x + __int_as_float(
        __builtin_amdgcn_ds_swizzle(__float_as_int(x), PAT));
}
__device__ __forceinline__ float red16(float x) {
    x = swz_add<0x041F>(x);   // xor 1
    x = swz_add<0x081F>(x);   // xor 2
    x = swz_add<0x101F>(x);   // xor 4
    x = swz_add<0x201F>(x);   // xor 8
    return x;                 // all 16 lanes hold the group sum
}

// Fast exact-GELU: erf via Abramowitz-Stegun 7.1.26 (|err| <= 1.5e-7)
__device__ __forceinline__ float fast_gelu(float x) {
    const float ax = fabsf(x) * 0.70710678118654752f;   // |x|/sqrt(2)
    const float t  = __builtin_amdgcn_rcpf(fmaf(0.3275911f, ax, 1.0f));
    float p = fmaf(1.061405429f, t, -1.453152027f);
    p = fmaf(p, t, 1.421413741f);
    p = fmaf(p, t, -0.284496736f);
    p = fmaf(p, t, 0.254829592f);
    p = p * t;
    const float e    = __expf(-ax * ax);
    const float erfa = fmaf(-p, e, 1.0f);               // erf(|x|/sqrt2)
    const float erfx = copysignf(erfa, x);
    return 0.5f * x * (1.0f + erfx);
}

// ---------------------------------------------------------------------------
// prep: W1 fp32 [768][1536] -> Wp bf16 [1536][768]; gw = gamma*W2 (fp32);
//       scal = {S1 = sum gamma*W2, S2 = sum beta*W2 + b2}
// ---------------------------------------------------------------------------
__global__ __launch_bounds__(256) void prep_kernel(
    const float* __restrict__ W1, const float* __restrict__ gamma,
    const float* __restrict__ beta, const float* __restrict__ W2,
    const float* __restrict__ b2,
    bf16* __restrict__ Wp, float* __restrict__ gw, float* __restrict__ scal)
{
    int bid = blockIdx.x;
    if (bid < 1152) {
        int t  = bid * 256 + threadIdx.x;
        int n  = t % II;
        int k0 = (t / II) * 4;
        bf16x4 v;
        v[0] = (bf16)W1[(size_t)(k0+0)*II + n];
        v[1] = (bf16)W1[(size_t)(k0+1)*II + n];
        v[2] = (bf16)W1[(size_t)(k0+2)*II + n];
        v[3] = (bf16)W1[(size_t)(k0+3)*II + n];
        *(bf16x4*)&Wp[(size_t)n*HH + k0] = v;
    } else if (bid == 1152) {
        for (int j = threadIdx.x; j < II; j += 256)
            gw[j] = gamma[j] * W2[j];
    } else {
        float s1 = 0.f, s2 = 0.f;
        for (int j = threadIdx.x; j < II; j += 256) {
            float w2 = W2[j];
            s1 += gamma[j] * w2;
            s2 += beta[j]  * w2;
        }
        #pragma unroll
        for (int off = 32; off; off >>= 1) {
            s1 += __shfl_down(s1, off, 64);
            s2 += __shfl_down(s2, off, 64);
        }
        __shared__ float a1[4], a2[4];
        int lane = threadIdx.x & 63, w = threadIdx.x >> 6;
        if (lane == 0) { a1[w] = s1; a2[w] = s2; }
        __syncthreads();
        if (threadIdx.x == 0) {
            scal[0] = a1[0] + a1[1] + a1[2] + a1[3];
            scal[1] = a2[0] + a2[1] + a2[2] + a2[3] + b2[0];
        }
    }
}

// ---------------------------------------------------------------------------
// gemm_part: 128x256 tile, BK=32, 16x16x32 bf16 MFMA, double-buffered LDS,
// 2-phase pipeline: issue next-tile loads (B via global_load_lds, A via
// float4->reg prefetch, T14 split) BEFORE current-tile ds_read+MFMA; one
// vmcnt(0)+barrier per K-step. LDS k-slot XOR-swizzled with (row>>1)&3
// (conflict-free read+write at 64 B row stride).
// Wave tile 64x128 (acc 4x8 f32x4). 2400 blocks = 400 mb x 6 nb,
// XCD-aware swizzle so 6 nb blocks sharing an A-tile run on one XCD.
// Epilogue: +b1, fast GELU, per-row partial LN stats -> part[s][nb][row].
// ---------------------------------------------------------------------------
__global__ __launch_bounds__(256, 2) void gemm_part(
    const float* __restrict__ Af, const bf16* __restrict__ Wp,
    const float* __restrict__ b1, const float* __restrict__ gw,
    float* __restrict__ part)
{
    __shared__ bf16  As[2 * 128 * 32];   // 16 KB (2 bufs)
    __shared__ bf16  Bs[2 * 256 * 32];   // 32 KB (2 bufs)
    __shared__ float sred[2][128][3];    // 3 KB

    const int tid  = threadIdx.x;
    // 2400 blocks = 8 XCDs x 300; 300 = 50 mb-groups x 6 nb
    const int lin  = (blockIdx.x & 7) * 300 + (blockIdx.x >> 3);
    const int mb   = lin / 6;
    const int nb   = lin % 6;
    const int lane = tid & 63;
    const int w    = tid >> 6;
    const int wm   = w >> 1;            // 0..1
    const int wn   = w & 1;             // 0..1
    const int m15  = lane & 15;
    const int q    = lane >> 4;         // 0..3
    const int row0 = mb * 128;

    // staging coords: 4 lanes per row; k-slot XOR-swizzled so that LDS
    // position p of row r holds k-slot (p ^ ((r>>1)&3)).
    const int r4   = lane >> 2;                         // 0..15
    const int ksel = (lane & 3) ^ ((lane >> 3) & 3);    // == (lane&3)^((row>>1)&3)
    const int kofs = ksel * 8;                          // elements

    const float* aP = Af + (size_t)(row0    + w*32 + r4) * HH + kofs;
    const bf16*  bP = Wp + (size_t)(nb*256 + w*64 + r4) * HH + kofs;

    const int asW = w*1024 + lane*8;    // A stage write base (bf16 idx)
    const int bsW = w*2048 + lane*8;    // B stage write base (bf16 idx)
    const int xsel8 = ((q ^ ((m15 >> 1) & 3)) << 3);    // read-side swizzle

    f32x4 acc[4][8] = {};

    // ---- prologue: stage kt=0 into buf 0 ----
    #pragma unroll
    for (int it = 0; it < 4; ++it)
        gld_lds16(bP + (size_t)it*16*HH, &Bs[bsW + it*512]);
    {
        float4 p00 = *(const float4*)(aP);
        float4 p01 = *(const float4*)(aP + 4);
        float4 p10 = *(const float4*)(aP + 16*HH);
        float4 p11 = *(const float4*)(aP + 16*HH + 4);
        asm volatile("s_waitcnt vmcnt(0)" ::: "memory");
        bf16x8 o0 = { (bf16)p00.x,(bf16)p00.y,(bf16)p00.z,(bf16)p00.w,
                      (bf16)p01.x,(bf16)p01.y,(bf16)p01.z,(bf16)p01.w };
        bf16x8 o1 = { (bf16)p10.x,(bf16)p10.y,(bf16)p10.z,(bf16)p10.w,
                      (bf16)p11.x,(bf16)p11.y,(bf16)p11.z,(bf16)p11.w };
        *(bf16x8*)&As[asW]       = o0;
        *(bf16x8*)&As[asW + 512] = o1;
    }
    __syncthreads();

    // ---- main loop: 23 pipelined K-steps + 1 peeled tail ----
    for (int kt = 0; kt < 23; ++kt) {
        const int cur = kt & 1, nxt = cur ^ 1;

        // issue next-tile loads first (overlap with compute below)
        const bf16*  bn = bP + (size_t)(kt + 1) * 32;
        const float* an = aP + (size_t)(kt + 1) * 32;
        #pragma unroll
        for (int it = 0; it < 4; ++it)
            gld_lds16(bn + (size_t)it*16*HH, &Bs[nxt*8192 + bsW + it*512]);
        float4 p00 = *(const float4*)(an);
        float4 p01 = *(const float4*)(an + 4);
        float4 p10 = *(const float4*)(an + 16*HH);
        float4 p11 = *(const float4*)(an + 16*HH + 4);

        // compute on current buffer
        bf16x8 af[4];
        #pragma unroll
        for (int mt = 0; mt < 4; ++mt)
            af[mt] = *(const bf16x8*)&As[cur*4096 + (wm*64 + mt*16 + m15)*32 + xsel8];
        #pragma unroll
        for (int nt = 0; nt < 8; ++nt) {
            bf16x8 bf = *(const bf16x8*)&Bs[cur*8192 + (wn*128 + nt*16 + m15)*32 + xsel8];
            #pragma unroll
            for (int mt = 0; mt < 4; ++mt)
                acc[mt][nt] = __builtin_amdgcn_mfma_f32_16x16x32_bf16(
                    af[mt], bf, acc[mt][nt], 0, 0, 0);
        }

        // finish A staging for next buffer (loads have been in flight)
        asm volatile("s_waitcnt vmcnt(0)" ::: "memory");
        {
            bf16x8 o0 = { (bf16)p00.x,(bf16)p00.y,(bf16)p00.z,(bf16)p00.w,
                          (bf16)p01.x,(bf16)p01.y,(bf16)p01.z,(bf16)p01.w };
            bf16x8 o1 = { (bf16)p10.x,(bf16)p10.y,(bf16)p10.z,(bf16)p10.w,
                          (bf16)p11.x,(bf16)p11.y,(bf16)p11.z,(bf16)p11.w };
            *(bf16x8*)&As[nxt*4096 + asW]       = o0;
            *(bf16x8*)&As[nxt*4096 + asW + 512] = o1;
        }
        __syncthreads();
    }
    {   // tail: kt=23, buffer 1, no prefetch
        const int cur = 1;
        bf16x8 af[4];
        #pragma unroll
        for (int mt = 0; mt < 4; ++mt)
            af[mt] = *(const bf16x8*)&As[cur*4096 + (wm*64 + mt*16 + m15)*32 + xsel8];
        #pragma unroll
        for (int nt = 0; nt < 8; ++nt) {
            bf16x8 bf = *(const bf16x8*)&Bs[cur*8192 + (wn*128 + nt*16 + m15)*32 + xsel8];
            #pragma unroll
            for (int mt = 0; mt < 4; ++mt)
                acc[mt][nt] = __builtin_amdgcn_mfma_f32_16x16x32_bf16(
                    af[mt], bf, acc[mt][nt], 0, 0, 0);
        }
    }

    // ---- epilogue: +b1, fast GELU, per-row partial stats over 256 cols ----
    float bv[8], gv[8];
    #pragma unroll
    for (int nt = 0; nt < 8; ++nt) {
        const int col = nb*256 + wn*128 + nt*16 + m15;
        bv[nt] = b1[col];
        gv[nt] = gw[col];
    }

    #pragma unroll
    for (int mt = 0; mt < 4; ++mt) {
        #pragma unroll
        for (int r = 0; r < 4; ++r) {
            float x0 = 0.f, x1 = 0.f, x2 = 0.f;
            #pragma unroll
            for (int nt = 0; nt < 8; ++nt) {
                // C/D layout: col = lane&15, row = q*4 + r
                float g = fast_gelu(acc[mt][nt][r] + bv[nt]);
                x0 += g; x1 += g * g; x2 += g * gv[nt];
            }
            x0 = red16(x0); x1 = red16(x1); x2 = red16(x2);
            if (m15 == 0) {
                const int rl = wm*64 + mt*16 + q*4 + r;   // 0..127
                sred[wn][rl][0] = x0;
                sred[wn][rl][1] = x1;
                sred[wn][rl][2] = x2;
            }
        }
    }
    __syncthreads();

    if (tid < 128) {
        const size_t rg = (size_t)row0 + tid;
        #pragma unroll
        for (int s = 0; s < 3; ++s)
            part[(size_t)s * 6 * MM + (size_t)nb * MM + rg]
                = sred[0][tid][s] + sred[1][tid][s];
    }
}

// ---------------------------------------------------------------------------
// score_pred: finish LN + sigmoid for the 100 rows of batch b, write scores,
// then pred = sum(scores), logits = one_hot(clamp(round(pred),0,15))
// ---------------------------------------------------------------------------
__global__ __launch_bounds__(128) void score_pred(
    const float* __restrict__ part, const float* __restrict__ scal,
    float* __restrict__ o_scores, float* __restrict__ o_pred,
    float* __restrict__ o_logits)
{
    const int b = blockIdx.x, t = threadIdx.x;
    float s = 0.f;
    if (t < NN) {
        const size_t row = (size_t)b * NN + t;
        float Sh = 0.f, Shh = 0.f, Shg = 0.f;
        #pragma unroll
        for (int j = 0; j < 6; ++j) {
            Sh  += part[(size_t)0*6*MM + (size_t)j*MM + row];
            Shh += part[(size_t)1*6*MM + (size_t)j*MM + row];
            Shg += part[(size_t)2*6*MM + (size_t)j*MM + row];
        }
        const float mu   = Sh * (1.0f / II);
        const float var  = Shh * (1.0f / II) - mu * mu;
        const float rstd = rsqrtf(var + 1e-5f);
        const float z    = rstd * (Shg - mu * scal[0]) + scal[1];
        s = 1.0f / (1.0f + __expf(-z));
        o_scores[row] = s;
    }
    float v = s;
    #pragma unroll
    for (int off = 32; off; off >>= 1) v += __shfl_down(v, off, 64);
    __shared__ float ssum[2];
    const int lane = t & 63, w = t >> 6;
    if (lane == 0) ssum[w] = v;
    __syncthreads();
    const float p = ssum[0] + ssum[1];
    if (t == 0) o_pred[b] = p;
    if (t < 16) {
        int aid = (int)rintf(p);
        aid = aid < 0 ? 0 : (aid > 15 ? 15 : aid);
        o_logits[b * 16 + t] = (t == aid) ? 1.0f : 0.0f;
    }
}

// ---------------------------------------------------------------------------
extern "C" void kernel_launch(void* const* d_in, const int* in_sizes, int n_in,
                              void* d_out, int out_size, void* d_ws, size_t ws_size,
                              hipStream_t stream)
{
    const float* v_emb = (const float*)d_in[0];
    const float* W1    = (const float*)d_in[1];
    const float* b1    = (const float*)d_in[2];
    const float* gamma = (const float*)d_in[3];
    const float* beta  = (const float*)d_in[4];
    const float* W2    = (const float*)d_in[5];
    const float* b2    = (const float*)d_in[6];

    char* ws = (char*)d_ws;
    size_t off = 0;
    bf16*  Wp   = (bf16*)(ws + off);  off += (size_t)II * HH * 2;      // 2.36 MB
    float* gw   = (float*)(ws + off); off += (size_t)II * 4;
    float* scal = (float*)(ws + off); off += 256;
    float* part = (float*)(ws + off); off += (size_t)MM * 18 * 4;      // 3.69 MB

    float* out       = (float*)d_out;
    float* o_scores  = out;            // 51200
    float* o_pred    = out + MM;       // 512
    float* o_logits  = out + MM + BB;  // 8192

    hipLaunchKernelGGL(prep_kernel, dim3(1154), dim3(256), 0, stream,
                       W1, gamma, beta, W2, b2, Wp, gw, scal);
    hipLaunchKernelGGL(gemm_part, dim3((MM / 128) * 6), dim3(256),
                       0, stream, v_emb, Wp, b1, gw, part);
    hipLaunchKernelGGL(score_pred, dim3(BB), dim3(128), 0, stream,
                       part, scal, o_scores, o_pred, o_logits);
}

// Round 2
// 422.662 us; speedup vs baseline: 1.0600x; 1.0600x over previous
//
#include <hip/hip_runtime.h>
#include <hip/hip_bf16.h>
#include <cstdint>
#include <cstddef>

// Problem constants
#define BB   512
#define NN   100
#define HH   768
#define II   1536
#define MM   (BB*NN)          // 51200 rows

typedef __bf16 bf16;
typedef __bf16 bf16x8 __attribute__((ext_vector_type(8)));
typedef float  f32x4  __attribute__((ext_vector_type(4)));

// async global -> LDS, 16B per lane (wave-uniform LDS base + lane*16)
__device__ __forceinline__ void gld_lds16(const bf16* g, bf16* l) {
    __builtin_amdgcn_global_load_lds(
        (const __attribute__((address_space(1))) void*)g,
        (__attribute__((address_space(3))) void*)l, 16, 0, 0);
}

// butterfly add over 16-lane groups via ds_swizzle (BitMode, single DS inst)
template <int PAT>
__device__ __forceinline__ float swz_add(float x) {
    return x + __int_as_float(
        __builtin_amdgcn_ds_swizzle(__float_as_int(x), PAT));
}
__device__ __forceinline__ float red16(float x) {
    x = swz_add<0x041F>(x);   // xor 1
    x = swz_add<0x081F>(x);   // xor 2
    x = swz_add<0x101F>(x);   // xor 4
    x = swz_add<0x201F>(x);   // xor 8
    return x;                 // all 16 lanes hold the group sum
}

// Fast exact-GELU: erf via Abramowitz-Stegun 7.1.26 (|err| <= 1.5e-7)
__device__ __forceinline__ float fast_gelu(float x) {
    const float ax = fabsf(x) * 0.70710678118654752f;   // |x|/sqrt(2)
    const float t  = __builtin_amdgcn_rcpf(fmaf(0.3275911f, ax, 1.0f));
    float p = fmaf(1.061405429f, t, -1.453152027f);
    p = fmaf(p, t, 1.421413741f);
    p = fmaf(p, t, -0.284496736f);
    p = fmaf(p, t, 0.254829592f);
    p = p * t;
    const float e    = __expf(-ax * ax);
    const float erfa = fmaf(-p, e, 1.0f);               // erf(|x|/sqrt2)
    const float erfx = copysignf(erfa, x);
    return 0.5f * x * (1.0f + erfx);
}

// ---------------------------------------------------------------------------
// prep_conv (fused):
//  bid <  6400 : v_emb fp32 [51200][768] -> Av bf16, chunk-XOR-swizzled:
//                stored 16B-chunk position p of row m holds global chunk
//                (p&~3) | ((p&3) ^ ((m>>1)&3))   (involution; baked so the
//                GEMM can use linear global_load_lds + swizzled ds_read)
//  bid <  6976 : W1 fp32 [768][1536] -> Wp bf16 [1536][768], transposed,
//                same per-row chunk-XOR swizzle (rows = n)
//  bid == 6976 : gw = gamma*W2
//  bid == 6977 : scal = {sum gamma*W2, sum beta*W2 + b2}
// ---------------------------------------------------------------------------
__global__ __launch_bounds__(256) void prep_conv(
    const float* __restrict__ v, const float* __restrict__ W1,
    const float* __restrict__ gamma, const float* __restrict__ beta,
    const float* __restrict__ W2, const float* __restrict__ b2,
    bf16* __restrict__ Av, bf16* __restrict__ Wp,
    float* __restrict__ gw, float* __restrict__ scal)
{
    const int bid = blockIdx.x;
    if (bid < 6400) {
        // A convert+swizzle: 8 rows per block, 32 threads/row, 3 chunks/thread
        const int r = threadIdx.x >> 5;          // 0..7
        const int j = threadIdx.x & 31;          // 0..31
        const size_t m = (size_t)bid * 8 + r;
        const float* src = v + m * HH;
        bf16* dst = Av + m * HH;
        const int x = (int)((m >> 1) & 3);
        #pragma unroll
        for (int u = 0; u < 3; ++u) {
            const int p = j * 3 + u;                       // stored pos 0..95
            const int g = (p & ~3) | ((p & 3) ^ x);        // content chunk
            float4 a = *(const float4*)(src + g * 8);
            float4 b = *(const float4*)(src + g * 8 + 4);
            bf16x8 o = { (bf16)a.x,(bf16)a.y,(bf16)a.z,(bf16)a.w,
                         (bf16)b.x,(bf16)b.y,(bf16)b.z,(bf16)b.w };
            *(bf16x8*)(dst + p * 8) = o;
        }
    } else if (bid < 6976) {
        // W1 transpose+convert+swizzle: thread -> one 16B output chunk
        const int t = (bid - 6400) * 256 + threadIdx.x;    // 0..147455
        const int n = t % II;                              // lane-consecutive
        const int g = t / II;                              // content chunk 0..95
        const int p = (g & ~3) | ((g & 3) ^ ((n >> 1) & 3));
        bf16x8 o;
        #pragma unroll
        for (int i = 0; i < 8; ++i)
            o[i] = (bf16)W1[(size_t)(g * 8 + i) * II + n]; // coalesced reads
        *(bf16x8*)&Wp[(size_t)n * HH + p * 8] = o;
    } else if (bid == 6976) {
        for (int j = threadIdx.x; j < II; j += 256)
            gw[j] = gamma[j] * W2[j];
    } else {
        float s1 = 0.f, s2 = 0.f;
        for (int j = threadIdx.x; j < II; j += 256) {
            float w2 = W2[j];
            s1 += gamma[j] * w2;
            s2 += beta[j]  * w2;
        }
        #pragma unroll
        for (int off = 32; off; off >>= 1) {
            s1 += __shfl_down(s1, off, 64);
            s2 += __shfl_down(s2, off, 64);
        }
        __shared__ float a1[4], a2[4];
        int lane = threadIdx.x & 63, w = threadIdx.x >> 6;
        if (lane == 0) { a1[w] = s1; a2[w] = s2; }
        __syncthreads();
        if (threadIdx.x == 0) {
            scal[0] = a1[0] + a1[1] + a1[2] + a1[3];
            scal[1] = a2[0] + a2[1] + a2[2] + a2[3] + b2[0];
        }
    }
}

// ---------------------------------------------------------------------------
// gemm_part: 128x128 tile, BK=32, 16x16x32 bf16 MFMA, double-buffered LDS,
// BOTH operands staged via global_load_lds from pre-swizzled bf16 sources
// (no register staging, no VALU convert in the loop). 24 K-steps; each step
// issues next-tile loads before compute, so the end-of-step vmcnt(0) drain
// waits on loads that had a full compute phase (mostly L2 hits) to land.
// LDS: 2*(8+8) KB + 3 KB = 35 KB -> 4 blocks/CU; acc[4][4] (64 AGPR) ->
// ~3 waves/SIMD by regs. Occupancy ~37%.
// Read-side XOR swizzle (q ^ ((m15>>1)&3)) matches the baked layout:
// 2-way bank aliasing max (free).
// Epilogue: +b1, fast GELU, per-row partial LN stats -> part[s][nb][row].
// ---------------------------------------------------------------------------
__global__ __launch_bounds__(256) void gemm_part(
    const bf16* __restrict__ Av, const bf16* __restrict__ Wp,
    const float* __restrict__ b1, const float* __restrict__ gw,
    float* __restrict__ part)
{
    __shared__ bf16  As[2][128 * 32];   // 16 KB
    __shared__ bf16  Bs[2][128 * 32];   // 16 KB
    __shared__ float sred[2][128][3];   // 3 KB

    const int tid  = threadIdx.x;
    // 4800 blocks = 8 XCDs x 600; 600 = 50 mb-groups x 12 nb (A-tile shared
    // by the 12 nb blocks on one XCD -> L2-hot A)
    const int lin  = (blockIdx.x & 7) * 600 + (blockIdx.x >> 3);
    const int mb   = lin / 12;
    const int nb   = lin % 12;
    const int lane = tid & 63;
    const int w    = tid >> 6;
    const int wm   = w >> 1;            // 0..1
    const int wn   = w & 1;             // 0..1
    const int m15  = lane & 15;
    const int q    = lane >> 4;         // 0..3
    const int row0 = mb * 128;

    // staging: thread t covers (row = it*64 + t/4, chunk = t&3), 16B each
    const int srow = tid >> 2;          // 0..63
    const int sc   = tid & 3;
    const bf16* aP = Av + (size_t)(row0     + srow) * HH + sc * 8;
    const bf16* bP = Wp + (size_t)(nb * 128 + srow) * HH + sc * 8;
    bf16* asD = &As[0][0] + tid * 8;    // + cur*4096 (+2048 for rows 64..127)
    bf16* bsD = &Bs[0][0] + tid * 8;

    const int xsel = (q ^ ((m15 >> 1) & 3)) * 8;   // read-side swizzle (elems)

    f32x4 acc[4][4] = {};

    // ---- prologue: stage kt=0 into buf 0 ----
    gld_lds16(aP,           asD);
    gld_lds16(aP + 64 * HH, asD + 2048);
    gld_lds16(bP,           bsD);
    gld_lds16(bP + 64 * HH, bsD + 2048);
    asm volatile("s_waitcnt vmcnt(0)" ::: "memory");
    __syncthreads();

    // ---- main loop: 23 pipelined K-steps + 1 peeled tail ----
    for (int kt = 0; kt < 23; ++kt) {
        const int cur = kt & 1, nxt = cur ^ 1;
        const int ko  = (kt + 1) * 32;

        // issue next-tile loads first (they complete under the MFMA phase)
        gld_lds16(aP + ko,           asD + nxt * 4096);
        gld_lds16(aP + ko + 64 * HH, asD + nxt * 4096 + 2048);
        gld_lds16(bP + ko,           bsD + nxt * 4096);
        gld_lds16(bP + ko + 64 * HH, bsD + nxt * 4096 + 2048);

        // compute on current buffer
        bf16x8 af[4];
        #pragma unroll
        for (int mt = 0; mt < 4; ++mt)
            af[mt] = *(const bf16x8*)&As[cur][(wm*64 + mt*16 + m15)*32 + xsel];
        #pragma unroll
        for (int nt = 0; nt < 4; ++nt) {
            bf16x8 bfr = *(const bf16x8*)&Bs[cur][(wn*64 + nt*16 + m15)*32 + xsel];
            #pragma unroll
            for (int mt = 0; mt < 4; ++mt)
                acc[mt][nt] = __builtin_amdgcn_mfma_f32_16x16x32_bf16(
                    af[mt], bfr, acc[mt][nt], 0, 0, 0);
        }

        asm volatile("s_waitcnt vmcnt(0)" ::: "memory");
        __syncthreads();
    }
    {   // tail: kt=23, buffer 1, no prefetch
        bf16x8 af[4];
        #pragma unroll
        for (int mt = 0; mt < 4; ++mt)
            af[mt] = *(const bf16x8*)&As[1][(wm*64 + mt*16 + m15)*32 + xsel];
        #pragma unroll
        for (int nt = 0; nt < 4; ++nt) {
            bf16x8 bfr = *(const bf16x8*)&Bs[1][(wn*64 + nt*16 + m15)*32 + xsel];
            #pragma unroll
            for (int mt = 0; mt < 4; ++mt)
                acc[mt][nt] = __builtin_amdgcn_mfma_f32_16x16x32_bf16(
                    af[mt], bfr, acc[mt][nt], 0, 0, 0);
        }
    }

    // ---- epilogue: +b1, fast GELU, per-row partial stats over 128 cols ----
    float bv[4], gv[4];
    #pragma unroll
    for (int nt = 0; nt < 4; ++nt) {
        const int col = nb*128 + wn*64 + nt*16 + m15;
        bv[nt] = b1[col];
        gv[nt] = gw[col];
    }

    #pragma unroll
    for (int mt = 0; mt < 4; ++mt) {
        #pragma unroll
        for (int r = 0; r < 4; ++r) {
            float x0 = 0.f, x1 = 0.f, x2 = 0.f;
            #pragma unroll
            for (int nt = 0; nt < 4; ++nt) {
                // C/D layout: col = lane&15, row = q*4 + r
                float g = fast_gelu(acc[mt][nt][r] + bv[nt]);
                x0 += g; x1 += g * g; x2 += g * gv[nt];
            }
            x0 = red16(x0); x1 = red16(x1); x2 = red16(x2);
            if (m15 == 0) {
                const int rl = wm*64 + mt*16 + q*4 + r;   // 0..127
                sred[wn][rl][0] = x0;
                sred[wn][rl][1] = x1;
                sred[wn][rl][2] = x2;
            }
        }
    }
    __syncthreads();

    if (tid < 128) {
        const size_t rg = (size_t)row0 + tid;
        #pragma unroll
        for (int s = 0; s < 3; ++s)
            part[(size_t)s * 12 * MM + (size_t)nb * MM + rg]
                = sred[0][tid][s] + sred[1][tid][s];
    }
}

// ---------------------------------------------------------------------------
// score_pred: finish LN + sigmoid for the 100 rows of batch b, write scores,
// then pred = sum(scores), logits = one_hot(clamp(round(pred),0,15))
// ---------------------------------------------------------------------------
__global__ __launch_bounds__(128) void score_pred(
    const float* __restrict__ part, const float* __restrict__ scal,
    float* __restrict__ o_scores, float* __restrict__ o_pred,
    float* __restrict__ o_logits)
{
    const int b = blockIdx.x, t = threadIdx.x;
    float s = 0.f;
    if (t < NN) {
        const size_t row = (size_t)b * NN + t;
        float Sh = 0.f, Shh = 0.f, Shg = 0.f;
        #pragma unroll
        for (int j = 0; j < 12; ++j) {
            Sh  += part[(size_t)0*12*MM + (size_t)j*MM + row];
            Shh += part[(size_t)1*12*MM + (size_t)j*MM + row];
            Shg += part[(size_t)2*12*MM + (size_t)j*MM + row];
        }
        const float mu   = Sh * (1.0f / II);
        const float var  = Shh * (1.0f / II) - mu * mu;
        const float rstd = rsqrtf(var + 1e-5f);
        const float z    = rstd * (Shg - mu * scal[0]) + scal[1];
        s = 1.0f / (1.0f + __expf(-z));
        o_scores[row] = s;
    }
    float v = s;
    #pragma unroll
    for (int off = 32; off; off >>= 1) v += __shfl_down(v, off, 64);
    __shared__ float ssum[2];
    const int lane = t & 63, w = t >> 6;
    if (lane == 0) ssum[w] = v;
    __syncthreads();
    const float p = ssum[0] + ssum[1];
    if (t == 0) o_pred[b] = p;
    if (t < 16) {
        int aid = (int)rintf(p);
        aid = aid < 0 ? 0 : (aid > 15 ? 15 : aid);
        o_logits[b * 16 + t] = (t == aid) ? 1.0f : 0.0f;
    }
}

// ---------------------------------------------------------------------------
extern "C" void kernel_launch(void* const* d_in, const int* in_sizes, int n_in,
                              void* d_out, int out_size, void* d_ws, size_t ws_size,
                              hipStream_t stream)
{
    const float* v_emb = (const float*)d_in[0];
    const float* W1    = (const float*)d_in[1];
    const float* b1    = (const float*)d_in[2];
    const float* gamma = (const float*)d_in[3];
    const float* beta  = (const float*)d_in[4];
    const float* W2    = (const float*)d_in[5];
    const float* b2    = (const float*)d_in[6];

    char* ws = (char*)d_ws;
    size_t off = 0;
    bf16*  Wp   = (bf16*)(ws + off);  off += (size_t)II * HH * 2;      // 2.36 MB
    float* gw   = (float*)(ws + off); off += (size_t)II * 4;
    float* scal = (float*)(ws + off); off += 256;
    float* part = (float*)(ws + off); off += (size_t)MM * 36 * 4;      // 7.37 MB
    bf16*  Av   = (bf16*)(ws + off);  off += (size_t)MM * HH * 2;      // 78.6 MB

    float* out       = (float*)d_out;
    float* o_scores  = out;            // 51200
    float* o_pred    = out + MM;       // 512
    float* o_logits  = out + MM + BB;  // 8192

    hipLaunchKernelGGL(prep_conv, dim3(6978), dim3(256), 0, stream,
                       v_emb, W1, gamma, beta, W2, b2, Av, Wp, gw, scal);
    hipLaunchKernelGGL(gemm_part, dim3((MM / 128) * 12), dim3(256),
                       0, stream, Av, Wp, b1, gw, part);
    hipLaunchKernelGGL(score_pred, dim3(BB), dim3(128), 0, stream,
                       part, scal, o_scores, o_pred, o_logits);
}